// Round 1
// baseline (237.889 us; speedup 1.0000x reference)
//
#include <hip/hip_runtime.h>
#include <math.h>

#define G  300
#define NS 256
#define NR 4096
#define CT 32   // interleaved texel channels: 0-7 density, 8-31 app

typedef _Float16 half16_t;
typedef _Float16 h8 __attribute__((ext_vector_type(8)));

// ---------------------------------------------------------------------------
// Prep: interleave density(8ch) + app(24ch) planes into fp16 texels [i][y][x][c]
// ---------------------------------------------------------------------------
__global__ __launch_bounds__(256) void prep_planes(
    const float* __restrict__ dp, const float* __restrict__ ap,
    half16_t* __restrict__ out)
{
  int t = blockIdx.x * blockDim.x + threadIdx.x;
  if (t >= 3 * G * G) return;
  int x  = t % G;
  int yi = t / G;
  int y  = yi % G;
  int i  = yi / G;
  const float* dpp = dp + ((size_t)(i * 8) * G + y) * G + x;
  const float* app = ap + ((size_t)(i * 24) * G + y) * G + x;
  h8 v[4];
#pragma unroll
  for (int c = 0; c < 8; ++c) v[c >> 3][c & 7] = (half16_t)dpp[(size_t)c * G * G];
#pragma unroll
  for (int c = 0; c < 24; ++c) {
    int cc = c + 8;
    v[cc >> 3][cc & 7] = (half16_t)app[(size_t)c * G * G];
  }
  h8* o = (h8*)(out + (size_t)t * CT);
#pragma unroll
  for (int m = 0; m < 4; ++m) o[m] = v[m];
}

__global__ __launch_bounds__(256) void prep_lines(
    const float* __restrict__ dl, const float* __restrict__ al,
    half16_t* __restrict__ out)
{
  int t = blockIdx.x * blockDim.x + threadIdx.x;
  if (t >= 3 * G) return;
  int p = t % G;
  int i = t / G;
  h8 v[4];
#pragma unroll
  for (int c = 0; c < 8; ++c) v[c >> 3][c & 7] = (half16_t)dl[(i * 8 + c) * G + p];
#pragma unroll
  for (int c = 0; c < 24; ++c) {
    int cc = c + 8;
    v[cc >> 3][cc & 7] = (half16_t)al[(i * 24 + c) * G + p];
  }
  h8* o = (h8*)(out + (size_t)t * CT);
#pragma unroll
  for (int m = 0; m < 4; ++m) o[m] = v[m];
}

// ---------------------------------------------------------------------------
// Main fused kernel: wave per ray. Quartet (4 lanes) per sample, 8 ch/lane.
// ---------------------------------------------------------------------------
__global__ __launch_bounds__(256) void tensorf_fused(
    const float* __restrict__ xyz, const float* __restrict__ zv,
    const half16_t* __restrict__ planes, const half16_t* __restrict__ lns,
    const float* __restrict__ dbw, const float* __restrict__ abw,
    const float* __restrict__ aabb, float* __restrict__ out)
{
  __shared__ float4 srgb[4][NS];

  const int wv   = threadIdx.x >> 6;
  const int lane = threadIdx.x & 63;
  const int ray  = (blockIdx.x << 2) + wv;
  const int q    = lane >> 2;   // quartet id: sample slot
  const int r    = lane & 3;    // channel group: 0 = density ch0-7, 1..3 = app

  // Per-lane basis weights: W[j][i*8+k].
  // r==0: j=0 holds density_basis_w, j=1,2 zero (outputs discarded via pack).
  // r>0 : j = rgb row, weights abw[j][i*24 + (r-1)*8 + k].
  float W[3][24];
  if (r == 0) {
#pragma unroll
    for (int m = 0; m < 24; ++m) { W[0][m] = dbw[m]; W[1][m] = 0.f; W[2][m] = 0.f; }
  } else {
#pragma unroll
    for (int j = 0; j < 3; ++j)
#pragma unroll
      for (int i = 0; i < 3; ++i)
#pragma unroll
        for (int k = 0; k < 8; ++k)
          W[j][i * 8 + k] = abw[j * 72 + i * 24 + (r - 1) * 8 + k];
  }

  const float a0x = aabb[0], a0y = aabb[1], a0z = aabb[2];
  const float ivx = 2.f / (aabb[3] - aabb[0]);
  const float ivy = 2.f / (aabb[4] - aabb[1]);
  const float ivz = 2.f / (aabb[5] - aabb[2]);

  const int MA[3] = {0, 0, 1};   // MAT_MODE first
  const int MB[3] = {1, 2, 2};   // MAT_MODE second
  const int MV[3] = {2, 1, 0};   // VEC_MODE

  const int ro = r * 8;

  for (int it = 0; it < NS / 16; ++it) {
    int s = it * 16 + q;
    const float* xp = xyz + ((size_t)ray * NS + s) * 3;
    float g[3];
    g[0] = (xp[0] - a0x) * ivx - 1.f;
    g[1] = (xp[1] - a0y) * ivy - 1.f;
    g[2] = (xp[2] - a0z) * ivz - 1.f;

    float acc0 = 0.f, acc1 = 0.f, acc2 = 0.f;
#pragma unroll
    for (int i = 0; i < 3; ++i) {
      float fx = (g[MA[i]] + 1.f) * (0.5f * (G - 1));
      float fy = (g[MB[i]] + 1.f) * (0.5f * (G - 1));
      float ft = (g[MV[i]] + 1.f) * (0.5f * (G - 1));
      float x0f = floorf(fx), y0f = floorf(fy), t0f = floorf(ft);
      float wx = fx - x0f, wy = fy - y0f, wt = ft - t0f;
      int x0 = min(max((int)x0f, 0), G - 1);
      int y0 = min(max((int)y0f, 0), G - 1);
      int t0 = min(max((int)t0f, 0), G - 1);
      int x1 = min(x0 + 1, G - 1);
      int y1 = min(y0 + 1, G - 1);
      int t1 = min(t0 + 1, G - 1);

      const half16_t* pb = planes + (size_t)i * G * G * CT;
      h8 t00 = *(const h8*)(pb + ((size_t)(y0 * G + x0)) * CT + ro);
      h8 t01 = *(const h8*)(pb + ((size_t)(y0 * G + x1)) * CT + ro);
      h8 t10 = *(const h8*)(pb + ((size_t)(y1 * G + x0)) * CT + ro);
      h8 t11 = *(const h8*)(pb + ((size_t)(y1 * G + x1)) * CT + ro);
      const half16_t* lb = lns + (size_t)i * G * CT + ro;
      h8 l0 = *(const h8*)(lb + (size_t)t0 * CT);
      h8 l1 = *(const h8*)(lb + (size_t)t1 * CT);

      float w00 = (1.f - wx) * (1.f - wy), w01 = wx * (1.f - wy);
      float w10 = (1.f - wx) * wy,         w11 = wx * wy;
      float wl0 = 1.f - wt;
#pragma unroll
      for (int k = 0; k < 8; ++k) {
        float pf = (float)t00[k] * w00 + (float)t01[k] * w01
                 + (float)t10[k] * w10 + (float)t11[k] * w11;
        float lf = (float)l0[k] * wl0 + (float)l1[k] * wt;
        float f  = pf * lf;
        acc0 += W[0][i * 8 + k] * f;
        acc1 += W[1][i * 8 + k] * f;
        acc2 += W[2][i * 8 + k] * f;
      }
    }
    // pack (sigma_feat, r, g, b) and reduce across the quartet
    float4 v;
    v.x = (r == 0) ? acc0 : 0.f;
    v.y = (r == 0) ? 0.f : acc0;
    v.z = (r == 0) ? 0.f : acc1;
    v.w = (r == 0) ? 0.f : acc2;
#pragma unroll
    for (int m = 1; m <= 2; m <<= 1) {
      v.x += __shfl_xor(v.x, m);
      v.y += __shfl_xor(v.y, m);
      v.z += __shfl_xor(v.z, m);
      v.w += __shfl_xor(v.w, m);
    }
    if (r == 0) srgb[wv][s] = v;
  }
  __syncthreads();

  // ---- per-ray transmittance scan: lane handles samples lane*4 .. lane*4+3
  const float* zp = zv + (size_t)ray * NS + lane * 4;
  float4 z4 = *(const float4*)zp;
  float znext = __shfl_down(z4.x, 1);
  float d[4];
  d[0] = z4.y - z4.x;
  d[1] = z4.z - z4.y;
  d[2] = z4.w - z4.z;
  d[3] = (lane == 63) ? d[2] : (znext - z4.w);

  float4 c[4];
  float al[4];
  float tl = 1.f;
#pragma unroll
  for (int j = 0; j < 4; ++j) {
    c[j] = srgb[wv][lane * 4 + j];
    float vs = c[j].x - 10.0f;  // DENSITY_SHIFT
    float sp = (vs > 0.f) ? (vs + log1pf(expf(-vs))) : log1pf(expf(vs));
    al[j] = 1.f - expf(-sp * (d[j] * 25.0f));  // DISTANCE_SCALE
    tl *= (1.f - al[j] + 1e-10f);
  }
  // inclusive prefix product across lanes -> exclusive start T
  float incl = tl;
#pragma unroll
  for (int off = 1; off < 64; off <<= 1) {
    float p = __shfl_up(incl, off);
    if (lane >= off) incl *= p;
  }
  float T = __shfl_up(incl, 1);
  if (lane == 0) T = 1.f;

  float ar = 0.f, ag = 0.f, ab = 0.f;
#pragma unroll
  for (int j = 0; j < 4; ++j) {
    float w = al[j] * T;
    ar += w * c[j].y;
    ag += w * c[j].z;
    ab += w * c[j].w;
    T *= (1.f - al[j] + 1e-10f);
  }
#pragma unroll
  for (int off = 32; off > 0; off >>= 1) {
    ar += __shfl_down(ar, off);
    ag += __shfl_down(ag, off);
    ab += __shfl_down(ab, off);
  }
  if (lane == 0) {
    out[ray * 3 + 0] = ar;
    out[ray * 3 + 1] = ag;
    out[ray * 3 + 2] = ab;
  }
}

// ---------------------------------------------------------------------------
extern "C" void kernel_launch(void* const* d_in, const int* in_sizes, int n_in,
                              void* d_out, int out_size, void* d_ws, size_t ws_size,
                              hipStream_t stream)
{
  const float* xyz  = (const float*)d_in[0];
  // d_in[1] = viewdirs (unused by reference output path)
  const float* zv   = (const float*)d_in[2];
  const float* dp   = (const float*)d_in[3];
  const float* dl   = (const float*)d_in[4];
  const float* ap   = (const float*)d_in[5];
  const float* al   = (const float*)d_in[6];
  const float* dbw  = (const float*)d_in[7];
  const float* abw  = (const float*)d_in[8];
  const float* aabb = (const float*)d_in[9];
  float* out = (float*)d_out;

  half16_t* planes16 = (half16_t*)d_ws;                    // 3*300*300*32 halves = 17.28 MB
  half16_t* lines16  = planes16 + (size_t)3 * G * G * CT;  // 28800 halves

  hipLaunchKernelGGL(prep_planes, dim3((3 * G * G + 255) / 256), dim3(256), 0, stream,
                     dp, ap, planes16);
  hipLaunchKernelGGL(prep_lines, dim3((3 * G + 255) / 256), dim3(256), 0, stream,
                     dl, al, lines16);
  hipLaunchKernelGGL(tensorf_fused, dim3(NR / 4), dim3(256), 0, stream,
                     xyz, zv, planes16, lines16, dbw, abw, aabb, out);
}